// Round 6
// baseline (371.215 us; speedup 1.0000x reference)
//
#include <hip/hip_runtime.h>
#include <hip/hip_bf16.h>
#include <stdint.h>

// B=8, N=2048, E=1024, H=16, D=64 -> M = B*N = 16384.
// qkv row layout per token: [3][H=16][D=64] = 3072 elems (6144 B)

typedef __attribute__((ext_vector_type(8))) short short8;
typedef __attribute__((ext_vector_type(8))) unsigned short ushort8;
typedef __attribute__((ext_vector_type(4))) unsigned short ushort4v;
typedef __attribute__((ext_vector_type(4))) float floatx4;

__device__ __forceinline__ unsigned short f2bf(float f) {
  union { float f; uint32_t u; } x; x.f = f;
  uint32_t u = x.u;
  return (unsigned short)((u + 0x7fffu + ((u >> 16) & 1u)) >> 16);  // RNE
}

// ---------------- fused fp32 -> bf16 cast ----------------
__global__ __launch_bounds__(256) void cvt_all(const float* __restrict__ x,
                                               const float* __restrict__ w1,
                                               const float* __restrict__ w2,
                                               unsigned short* __restrict__ xb,
                                               unsigned short* __restrict__ w1b,
                                               unsigned short* __restrict__ w2b) {
  int i = blockIdx.x * 256 + threadIdx.x;
  const float* src;
  unsigned short* dst;
  if (i < 2097152) {
    src = x; dst = xb;
  } else if (i < 2097152 + 393216) {
    i -= 2097152; src = w1; dst = w1b;
  } else {
    i -= 2490368; src = w2; dst = w2b;
  }
  long base = (long)i * 8;
  const float4* p = (const float4*)(src + base);
  float4 a = p[0], b = p[1];
  ushort8 r;
  r[0] = f2bf(a.x); r[1] = f2bf(a.y); r[2] = f2bf(a.z); r[3] = f2bf(a.w);
  r[4] = f2bf(b.x); r[5] = f2bf(b.y); r[6] = f2bf(b.z); r[7] = f2bf(b.w);
  *(ushort8*)(dst + base) = r;
}

// ---------------- async global->LDS, 16B per lane ----------------
__device__ __forceinline__ void gl2lds16(const void* g, void* l) {
  __builtin_amdgcn_global_load_lds(
      (const uint32_t __attribute__((address_space(1)))*)g,
      (uint32_t __attribute__((address_space(3)))*)(uint32_t)(uintptr_t)l,
      16, 0, 0);
}

// ---------------- bf16 GEMM: C = A*B^T + bias (256x256 tile) ----------------
// Round-6: B LEAVES LDS. Round 3/4 both pinned MfmaUtil at 41% because the
// LDS read port was ~93% loaded (96 ds_read_b128/window/CU ~= 1150 cyc vs
// 1240 cyc MFMA): 2M x 4N tiling is LDS-read-bound by construction. B (the
// weight matrix, <=6MB, L2-resident) is now loaded per-wave straight into
// VGPRs (global_load_dwordx4 of B^T[col][k-octet]), double-buffered one
// window ahead so L2 latency hides under the MFMAs. LDS keeps only A:
// 4-deep ring of 16KB bufs (64KB); LDS reads drop to 64KB/window (~60% of
// MFMA) and staging writes halve.
// vmcnt ledger (in-order queue mixes B-reg-loads and A-stage DMA):
//   window kt issues: [8 ds_read A] ... [4x B(kt+1) global] [2x A-stage(kt+3)]
//   steady end-of-window wait vmcnt(2): retires B(kt+1) (+A(kt+2)), leaves
//   A(kt+3) flying. Tail: vmcnt(0) at kt=NT-3, NT-2; none at NT-1.
// lgkm pipeline (A-only, counted): issue af0-3; lgkm(2)->c0(af0,1); issue
// af4,5; lgkm(2)->c1; issue af6,7+B+stage; lgkm(2)->c2; lgkm(0)->c3.
// One s_barrier per window. Both-sides XOR swizzle on A unchanged.
template <bool OUT_BF16>
__device__ __forceinline__ void gemm256_core(const unsigned short* __restrict__ A,
                                             const unsigned short* __restrict__ Bm,
                                             const float* __restrict__ bias,
                                             void* __restrict__ Cout,
                                             int K, int ncols, int ldc) {
  __shared__ __align__(16) char lA[65536];   // 4 ring bufs x 16KB (A only)

  const int id = blockIdx.x;
  const int local = id % (8 * ncols);
  const int brow = (id / (8 * ncols)) * 8 + (local & 7);
  const int bcol = local >> 3;
  const long row0 = (long)brow * 256;
  const long col0 = (long)bcol * 256;

  const int tid = threadIdx.x;
  const int lane = tid & 63;
  const int wave = tid >> 6;
  const int wm = wave >> 2;   // 0..1 (M half)
  const int wn = wave & 3;    // 0..3 (N quarter)
  const int l15 = lane & 15;
  const int lk = lane >> 4;   // k-octet (16B chunk index)

  // Load bias FIRST and drain, so the vmcnt queue holds loop loads only.
  float bv[4];
#pragma unroll
  for (int n = 0; n < 4; ++n) bv[n] = bias[col0 + wn * 64 + n * 16 + l15];
  asm volatile("s_waitcnt vmcnt(0)" ::: "memory");

  // A staging: thread t covers LDS row t>>2 (per 128-row round), chunk t&3.
  // global chunk pre-swizzled: gch = (t&3) ^ ((row>>1)&3) = (t&3) ^ ((t>>3)&3)
  const int trow = tid >> 2;
  const int gch = (tid & 3) ^ ((tid >> 3) & 3);
  const unsigned short* gA = A + (row0 + trow) * (long)K + gch * 8;
  const long rstep = (long)128 * K;   // staging round 1: rows +128
  char* dA = lA + tid * 16;

  // B fragment source: lane reads B^T[col][k-octet], 16B; n stride = 16*K.
  const unsigned short* gBf = Bm + (col0 + wn * 64 + l15) * (long)K + lk * 8;

  // A fragment read offset (swizzled chunk; (row>>1)&3 == (l15>>1)&3)
  const int ch = ((lk ^ ((l15 >> 1) & 3)) << 4);
  const int aoff = (wm * 128 + l15) * 64 + ch;   // + m*1024 + buf*16384

  floatx4 acc[8][4] = {};
  const int NT = K >> 5;   // K-tiles of 32

  short8 bcur[4], bnxt[4];
  // prologue: stage A tiles 0,1,2; load B(0) into bcur
#pragma unroll
  for (int t = 0; t < 3; ++t) {
    const long ko = (long)t * 32;
    gl2lds16(gA + ko, dA + t * 16384);
    gl2lds16(gA + rstep + ko, dA + t * 16384 + 8192);
  }
#pragma unroll
  for (int n = 0; n < 4; ++n) bcur[n] = *(const short8*)(gBf + (long)n * 16 * K);
  asm volatile("s_waitcnt vmcnt(0)" ::: "memory");
  __builtin_amdgcn_s_barrier();

#pragma unroll 1
  for (int kt = 0; kt < NT; ++kt) {
    const char* bufA = lA + (kt & 3) * 16384;
    const bool stage = (kt + 3 < NT);
    const bool loadB = (kt + 1 < NT);
    const long ko = (long)(kt + 3) * 32;
    const int sb = ((kt + 3) & 3) * 16384;

    short8 af[8];
    // issue af0-3 (cluster 0 needs af0,1; cluster 1 reads in flight)
    af[0] = *(const short8*)(bufA + aoff + 0 * 1024);
    af[1] = *(const short8*)(bufA + aoff + 1 * 1024);
    af[2] = *(const short8*)(bufA + aoff + 2 * 1024);
    af[3] = *(const short8*)(bufA + aoff + 3 * 1024);
    __builtin_amdgcn_sched_barrier(0);
    asm volatile("s_waitcnt lgkmcnt(2)" ::: "memory");   // af0,1 done
    __builtin_amdgcn_sched_barrier(0);
    __builtin_amdgcn_s_setprio(1);
#pragma unroll
    for (int n = 0; n < 4; ++n) {
      acc[0][n] = __builtin_amdgcn_mfma_f32_16x16x32_bf16(af[0], bcur[n], acc[0][n], 0, 0, 0);
      acc[1][n] = __builtin_amdgcn_mfma_f32_16x16x32_bf16(af[1], bcur[n], acc[1][n], 0, 0, 0);
    }
    __builtin_amdgcn_s_setprio(0);
    af[4] = *(const short8*)(bufA + aoff + 4 * 1024);
    af[5] = *(const short8*)(bufA + aoff + 5 * 1024);
    asm volatile("s_waitcnt lgkmcnt(2)" ::: "memory");   // af2,3 done
    __builtin_amdgcn_sched_barrier(0);
    __builtin_amdgcn_s_setprio(1);
#pragma unroll
    for (int n = 0; n < 4; ++n) {
      acc[2][n] = __builtin_amdgcn_mfma_f32_16x16x32_bf16(af[2], bcur[n], acc[2][n], 0, 0, 0);
      acc[3][n] = __builtin_amdgcn_mfma_f32_16x16x32_bf16(af[3], bcur[n], acc[3][n], 0, 0, 0);
    }
    __builtin_amdgcn_s_setprio(0);
    // issue af6,7 + next-window B + next-ring A stage (all in flight over c2/c3)
    af[6] = *(const short8*)(bufA + aoff + 6 * 1024);
    af[7] = *(const short8*)(bufA + aoff + 7 * 1024);
    if (loadB) {
#pragma unroll
      for (int n = 0; n < 4; ++n)
        bnxt[n] = *(const short8*)(gBf + (long)n * 16 * K + (kt + 1) * 32);
    }
    if (stage) {
      gl2lds16(gA + ko, dA + sb);
      gl2lds16(gA + rstep + ko, dA + sb + 8192);
    }
    __builtin_amdgcn_sched_barrier(0);
    asm volatile("s_waitcnt lgkmcnt(2)" ::: "memory");   // af4,5 done
    __builtin_amdgcn_sched_barrier(0);
    __builtin_amdgcn_s_setprio(1);
#pragma unroll
    for (int n = 0; n < 4; ++n) {
      acc[4][n] = __builtin_amdgcn_mfma_f32_16x16x32_bf16(af[4], bcur[n], acc[4][n], 0, 0, 0);
      acc[5][n] = __builtin_amdgcn_mfma_f32_16x16x32_bf16(af[5], bcur[n], acc[5][n], 0, 0, 0);
    }
    __builtin_amdgcn_s_setprio(0);
    asm volatile("s_waitcnt lgkmcnt(0)" ::: "memory");   // af6,7 done
    __builtin_amdgcn_sched_barrier(0);
    __builtin_amdgcn_s_setprio(1);
#pragma unroll
    for (int n = 0; n < 4; ++n) {
      acc[6][n] = __builtin_amdgcn_mfma_f32_16x16x32_bf16(af[6], bcur[n], acc[6][n], 0, 0, 0);
      acc[7][n] = __builtin_amdgcn_mfma_f32_16x16x32_bf16(af[7], bcur[n], acc[7][n], 0, 0, 0);
    }
    __builtin_amdgcn_s_setprio(0);
    __builtin_amdgcn_sched_barrier(0);
    // end-of-window counted wait (see ledger in header comment)
    if (kt < NT - 3) { asm volatile("s_waitcnt vmcnt(2)" ::: "memory"); }
    else if (kt < NT - 1) { asm volatile("s_waitcnt vmcnt(0)" ::: "memory"); }
    if (loadB) {
#pragma unroll
      for (int n = 0; n < 4; ++n) bcur[n] = bnxt[n];
    }
    __builtin_amdgcn_s_barrier();
  }

  // epilogue: C/D layout of 16x16x32: col = lane&15, row = (lane>>4)*4 + reg
  const long crow0 = row0 + wm * 128 + lk * 4;
  const long ccol0 = col0 + wn * 64 + l15;
#pragma unroll
  for (int m = 0; m < 8; ++m)
#pragma unroll
    for (int n = 0; n < 4; ++n)
#pragma unroll
      for (int r = 0; r < 4; ++r) {
        const long row = crow0 + m * 16 + r;
        const long col = ccol0 + n * 16;
        const float v = acc[m][n][r] + bv[n];
        if (OUT_BF16)
          ((unsigned short*)Cout)[row * ldc + col] = f2bf(v);
        else
          ((float*)Cout)[row * ldc + col] = v;
      }
}

__global__ __launch_bounds__(512, 2) void gemm_qkv(const unsigned short* __restrict__ A,
                                                   const unsigned short* __restrict__ Bm,
                                                   const float* __restrict__ bias,
                                                   unsigned short* __restrict__ Cout, int K) {
  gemm256_core<true>(A, Bm, bias, Cout, K, 12, 3072);
}
__global__ __launch_bounds__(512, 2) void gemm_out(const unsigned short* __restrict__ A,
                                                   const unsigned short* __restrict__ Bm,
                                                   const float* __restrict__ bias,
                                                   float* __restrict__ Cout, int K) {
  gemm256_core<false>(A, Bm, bias, Cout, K, 4, 1024);
}

// ---------------- per-token cross-head attention v4: MFMA ----------------
// (unchanged from round 5 -- passed, absmax 0.0039)
__global__ __launch_bounds__(256) void attn_kernel(const unsigned short* __restrict__ qkv,
                                                   unsigned short* __restrict__ out2) {
  __shared__ __align__(16) char lds[4 * 6144];  // 24 KB
  const int tid = threadIdx.x;
  const int wave = tid >> 6;
  const int lane = tid & 63;
  const int token = blockIdx.x * 4 + wave;
  const int l15 = lane & 15;
  const int lk = lane >> 4;
  const int b = token >> 11;
  const int s = token & 2047;

  const char* gbase = (const char*)qkv + (long)token * 6144;
  char* lbase = lds + wave * 6144;
#pragma unroll
  for (int p = 0; p < 6; p++) {
    const int o = p * 1024 + lane * 16;          // linear LDS dest offset
    const int row = o >> 7;                      // 128B row within token
    const int chs = ((o >> 4) & 7) ^ (row & 7);  // pre-swizzled source chunk
    const int src = (o & ~127) | (chs << 4);
    gl2lds16(gbase + src, lbase + o);
  }
  __syncthreads();

  // ---- QK^T (swapped): eT[j][q] = sum_d K[j][d] Q[q][d] ----
  const int sw = l15 & 7;
  const char* qrow = lbase + l15 * 128;
  const char* krow = lbase + 2048 + l15 * 128;
  const short8 kf0 = *(const short8*)(krow + ((lk ^ sw) << 4));
  const short8 kf1 = *(const short8*)(krow + (((lk + 4) ^ sw) << 4));
  const short8 qf0 = *(const short8*)(qrow + ((lk ^ sw) << 4));
  const short8 qf1 = *(const short8*)(qrow + (((lk + 4) ^ sw) << 4));
  floatx4 e = {};
  e = __builtin_amdgcn_mfma_f32_16x16x32_bf16(kf0, qf0, e, 0, 0, 0);
  e = __builtin_amdgcn_mfma_f32_16x16x32_bf16(kf1, qf1, e, 0, 0, 0);

  // ---- softmax over j (4 regs + lanes ^16, ^32); q = l15 stays lane-local ----
  float ev[4];
#pragma unroll
  for (int r = 0; r < 4; ++r) ev[r] = e[r] * 0.03125f;  // / sqrt(1024)
  float mx = fmaxf(fmaxf(ev[0], ev[1]), fmaxf(ev[2], ev[3]));
  mx = fmaxf(mx, __shfl_xor(mx, 16));
  mx = fmaxf(mx, __shfl_xor(mx, 32));
  float sum = 0.f;
#pragma unroll
  for (int r = 0; r < 4; ++r) { ev[r] = __expf(ev[r] - mx); sum += ev[r]; }
  sum += __shfl_xor(sum, 16);
  sum += __shfl_xor(sum, 32);
  const float inv = 1.f / sum;

  // ---- assemble attT B-frag (j-octet lk from lanes (l15,2lk),(l15,2lk+1)) ----
  const uint32_t pa = (uint32_t)f2bf(ev[0] * inv) | ((uint32_t)f2bf(ev[1] * inv) << 16);
  const uint32_t pb = (uint32_t)f2bf(ev[2] * inv) | ((uint32_t)f2bf(ev[3] * inv) << 16);
  const int src0 = (l15 + 32 * lk) & 63;
  uint32_t w0 = __shfl(pa, src0);
  uint32_t w1 = __shfl(pb, src0);
  uint32_t w2 = __shfl(pa, (src0 + 16) & 63);
  uint32_t w3 = __shfl(pb, (src0 + 16) & 63);
  if (lk >= 2) { w0 = 0; w1 = 0; w2 = 0; w3 = 0; }  // zero-pad K 16->32
  union { short8 s8; uint32_t u[4]; } attf;
  attf.u[0] = w0; attf.u[1] = w1; attf.u[2] = w2; attf.u[3] = w3;

  // ---- PV: out^T[d][q] = sum_j V^T[d][j] attT[j][q], 4 d-chunks of 16 ----
  const long orow = (long)b * 2048 + l15 * 128 + (s >> 4);
  unsigned short* op = out2 + orow * 1024 + (long)(s & 15) * 64;
#pragma unroll
  for (int c = 0; c < 4; ++c) {
    union { short8 s8; unsigned short us[8]; } vf;
    if (lk < 2) {
      const int byte_in = (c * 16 + l15) * 2;    // byte within V row (d dim)
#pragma unroll
      for (int i = 0; i < 8; ++i) {
        const int j = lk * 8 + i;
        const int chv = ((byte_in >> 4) ^ (j & 7));  // V rows are token-rows 32+j
        vf.us[i] = *(const unsigned short*)(lbase + 4096 + j * 128 + (chv << 4) +
                                            (byte_in & 15));
      }
    } else {
#pragma unroll
      for (int i = 0; i < 8; ++i) vf.us[i] = 0;    // zero-pad K 16->32
    }
    floatx4 o = {};
    o = __builtin_amdgcn_mfma_f32_16x16x32_bf16(vf.s8, attf.s8, o, 0, 0, 0);
    // lane: out[d = c*16 + lk*4 + r][head q = l15]
    ushort4v r4;
#pragma unroll
    for (int r = 0; r < 4; ++r) r4[r] = f2bf(o[r]);
    *(ushort4v*)(op + c * 16 + lk * 4) = r4;
  }
}

extern "C" void kernel_launch(void* const* d_in, const int* in_sizes, int n_in,
                              void* d_out, int out_size, void* d_ws, size_t ws_size,
                              hipStream_t stream) {
  const float* x    = (const float*)d_in[0];  // [8,2048,1024]
  const float* Wqkv = (const float*)d_in[1];  // [3072,1024]
  const float* bqkv = (const float*)d_in[2];  // [3072]
  const float* Wo   = (const float*)d_in[3];  // [1024,1024]
  const float* bo   = (const float*)d_in[4];  // [1024]
  float* out = (float*)d_out;                 // [8,2048,1024] fp32

  char* ws = (char*)d_ws;
  unsigned short* x_bf    = (unsigned short*)(ws);              // 32 MB
  unsigned short* wqkv_bf = (unsigned short*)(ws + 33554432);   // 6 MB
  unsigned short* wo_bf   = (unsigned short*)(ws + 39845888);   // 2 MB
  unsigned short* qkv_bf  = (unsigned short*)(ws + 41943040);   // 96 MB
  unsigned short* out2_bf = (unsigned short*)(ws + 142606336);  // 32 MB

  cvt_all<<<10240, 256, 0, stream>>>(x, Wqkv, Wo, x_bf, wqkv_bf, wo_bf);

  // qkv = x @ Wqkv^T + bqkv  (M=16384, N=3072, K=1024): 64 x 12 tiles of 256^2
  gemm_qkv<<<64 * 12, 512, 0, stream>>>(x_bf, wqkv_bf, bqkv, qkv_bf, 1024);

  // one wave per token: 16384 tokens / 4 waves per block
  attn_kernel<<<4096, 256, 0, stream>>>(qkv_bf, out2_bf);

  // out = out2 @ Wo^T + bo  (M=16384, N=1024, K=1024): 64 x 4 tiles of 256^2
  gemm_out<<<64 * 4, 512, 0, stream>>>(out2_bf, wo_bf, bo, out, 1024);
}

// Round 7
// 297.958 us; speedup vs baseline: 1.2459x; 1.2459x over previous
//
#include <hip/hip_runtime.h>
#include <hip/hip_bf16.h>
#include <stdint.h>

// B=8, N=2048, E=1024, H=16, D=64 -> M = B*N = 16384.
// qkv row layout per token: [3][H=16][D=64] = 3072 elems (6144 B)

typedef __attribute__((ext_vector_type(8))) short short8;
typedef __attribute__((ext_vector_type(8))) unsigned short ushort8;
typedef __attribute__((ext_vector_type(4))) unsigned short ushort4v;
typedef __attribute__((ext_vector_type(4))) float floatx4;

__device__ __forceinline__ unsigned short f2bf(float f) {
  union { float f; uint32_t u; } x; x.f = f;
  uint32_t u = x.u;
  return (unsigned short)((u + 0x7fffu + ((u >> 16) & 1u)) >> 16);  // RNE
}

// ---------------- fused fp32 -> bf16 cast ----------------
__global__ __launch_bounds__(256) void cvt_all(const float* __restrict__ x,
                                               const float* __restrict__ w1,
                                               const float* __restrict__ w2,
                                               unsigned short* __restrict__ xb,
                                               unsigned short* __restrict__ w1b,
                                               unsigned short* __restrict__ w2b) {
  int i = blockIdx.x * 256 + threadIdx.x;
  const float* src;
  unsigned short* dst;
  if (i < 2097152) {
    src = x; dst = xb;
  } else if (i < 2097152 + 393216) {
    i -= 2097152; src = w1; dst = w1b;
  } else {
    i -= 2490368; src = w2; dst = w2b;
  }
  long base = (long)i * 8;
  const float4* p = (const float4*)(src + base);
  float4 a = p[0], b = p[1];
  ushort8 r;
  r[0] = f2bf(a.x); r[1] = f2bf(a.y); r[2] = f2bf(a.z); r[3] = f2bf(a.w);
  r[4] = f2bf(b.x); r[5] = f2bf(b.y); r[6] = f2bf(b.z); r[7] = f2bf(b.w);
  *(ushort8*)(dst + base) = r;
}

// ---------------- async global->LDS, 16B per lane ----------------
__device__ __forceinline__ void gl2lds16(const void* g, void* l) {
  __builtin_amdgcn_global_load_lds(
      (const uint32_t __attribute__((address_space(1)))*)g,
      (uint32_t __attribute__((address_space(3)))*)(uint32_t)(uintptr_t)l,
      16, 0, 0);
}

// ---------------- bf16 GEMM: C = A*B^T + bias (256x256 tile) ----------------
// Round-7: faithful port of the PROVEN m201 8-phase template (1563 TF @4k).
// BK=64, 2 LDS bufs by tile parity (even->buf0, odd->buf1); each buf holds
// A[2 khalves][256 rows][4 chunks] + B[2 khalves][256 cols][4 chunks], 64KB.
// Iteration = 2 tiles (t even, t+1), 8 phases of (tile, kh, mh):
//   {4-or-8 ds_read_b128 ; stage ONE k-half (2 gl2lds) ; barrier ;
//    lgkmcnt(0) ; setprio(1) ; 16 MFMA 16x16x32 ; setprio(0) ;
//    [even phase: vmcnt(8)] ; barrier}
// Stage schedule (k-half granularity is what makes a 2-buf ring free one
// region EVERY phase):   ph1:A(t+1,k1)  ph2:B(t+1,k1)  ph3:A(t+2,k0)
//   ph4:B(t+2,k0)  ph5:A(t+2,k1)  ph6:B(t+2,k1)  ph7:A(t+3,k0)  ph8:B(t+3,k0)
// WAR: each stage's target region had its last read 1+ phase earlier (barrier
// between). RAW/vmcnt ledger: 6 stages (12 loads) in flight steady-state;
// vmcnt(8) at even phases retires exactly the 2 stages read next phase.
// Tail (last iter): stages ph3-8 skipped; vmcnt 8 (ph2), 4 (ph4), 0 (ph6).
// Swizzle (both sides): chunk c stored at c ^ ((row>>1)&3); staging source
// pre-swizzled (linear gl2lds dest), reads apply same XOR (0 conflicts, r3-5).
// Grid: 1D group-of-8-rows so XCD=id%8 pins one A panel per group.
template <bool OUT_BF16>
__device__ __forceinline__ void gemm256_core(const unsigned short* __restrict__ A,
                                             const unsigned short* __restrict__ Bm,
                                             const float* __restrict__ bias,
                                             void* __restrict__ Cout,
                                             int K, int ncols, int ldc) {
  __shared__ __align__(16) char lds[131072];

  const int id = blockIdx.x;
  const int local = id % (8 * ncols);
  const int brow = (id / (8 * ncols)) * 8 + (local & 7);
  const int bcol = local >> 3;
  const long row0 = (long)brow * 256;
  const long col0 = (long)bcol * 256;

  const int tid = threadIdx.x;
  const int lane = tid & 63;
  const int wave = tid >> 6;
  const int wm = wave >> 2;   // 0..1 (M half)
  const int wn = wave & 3;    // 0..3 (N quarter)
  const int l15 = lane & 15;
  const int lk = lane >> 4;   // k-octet within a k-step (16B chunk)
  const int tid16 = tid * 16;

  // bias first, drained, so the vmcnt queue holds staging loads only
  float bv[4];
#pragma unroll
  for (int n = 0; n < 4; ++n) bv[n] = bias[col0 + wn * 64 + n * 16 + l15];
  asm volatile("s_waitcnt vmcnt(0)" ::: "memory");

  // staging: thread t -> row tid>>2 (and +128), chunk tid&3 of a 16KB k-half
  // pre-swizzled global chunk: gch = (tid&3) ^ ((row>>1)&3) = (tid&3)^((tid>>3)&3)
  const int trow = tid >> 2;
  const int gch = (tid & 3) ^ ((tid >> 3) & 3);
  const unsigned short* gA = A + (row0 + trow) * (long)K + gch * 8;
  const unsigned short* gB = Bm + (col0 + trow) * (long)K + gch * 8;
  const long rstep = (long)128 * K;

#define STAGE_A(kt, h) do { \
    const unsigned short* s_ = gA + (kt) * 64 + (h) * 32; \
    char* d_ = lds + (((kt) & 1) << 16) + ((h) << 14) + tid16; \
    gl2lds16(s_, d_); gl2lds16(s_ + rstep, d_ + 8192); } while (0)
#define STAGE_B(kt, h) do { \
    const unsigned short* s_ = gB + (kt) * 64 + (h) * 32; \
    char* d_ = lds + (((kt) & 1) << 16) + 32768 + ((h) << 14) + tid16; \
    gl2lds16(s_, d_); gl2lds16(s_ + 8192 /*dummy keep shape*/ - 8192 + rstep, d_ + 8192); } while (0)

  // fragment read bases: row = wm*128 + mh*64 + m*16 + l15 (A),
  // col = wn*64 + n*16 + l15 (B); chunk = lk ^ ((l15>>1)&3) (swizzled)
  const int chA = (lk ^ ((l15 >> 1) & 3)) << 4;
  const int aBase = wm * 8192 + l15 * 64 + chA;           // + mh*4096 + m*1024
  const int bBase = 32768 + wn * 4096 + l15 * 64 + chA;   // + n*1024

#define RD8(off) (*(const short8*)(lds + (off)))
#define SBAR __builtin_amdgcn_sched_barrier(0)
#define SYNC1 do { SBAR; __builtin_amdgcn_s_barrier(); \
    asm volatile("s_waitcnt lgkmcnt(0)" ::: "memory"); SBAR; } while (0)
#define MFMA16(M0) do { __builtin_amdgcn_s_setprio(1); \
    _Pragma("unroll") for (int m = 0; m < 4; ++m) \
    _Pragma("unroll") for (int n = 0; n < 4; ++n) \
      acc[(M0) + m][n] = __builtin_amdgcn_mfma_f32_16x16x32_bf16(af[m], bf[n], acc[(M0) + m][n], 0, 0, 0); \
    __builtin_amdgcn_s_setprio(0); SBAR; } while (0)
#define VMC(N) asm volatile("s_waitcnt vmcnt(" #N ")" ::: "memory")
#define EBAR __builtin_amdgcn_s_barrier()

  floatx4 acc[8][4] = {};
  const int NT = K >> 6;        // K-tiles of 64
  const int NI = NT >> 1;       // iterations of 2 tiles

  // prologue: A(0,k0) B(0,k0) A(0,k1) B(0,k1) A(1,k0) B(1,k0); retire first 2
  STAGE_A(0, 0); STAGE_B(0, 0);
  STAGE_A(0, 1); STAGE_B(0, 1);
  STAGE_A(1, 0); STAGE_B(1, 0);
  VMC(8);
  EBAR;

#pragma unroll 1
  for (int I = 0; I < NI; ++I) {
    const int t = 2 * I;
    const bool more = (I + 1 < NI);
    short8 af[4], bf[4];

    // ---- ph1: (t, k0, m0); stage A(t+1, k1) ----
#pragma unroll
    for (int n = 0; n < 4; ++n) bf[n] = RD8(bBase + n * 1024);
#pragma unroll
    for (int m = 0; m < 4; ++m) af[m] = RD8(aBase + m * 1024);
    STAGE_A(t + 1, 1);
    SYNC1; MFMA16(0); EBAR;

    // ---- ph2: (t, k0, m1); stage B(t+1, k1); vmcnt(8) ----
#pragma unroll
    for (int m = 0; m < 4; ++m) af[m] = RD8(aBase + 4096 + m * 1024);
    STAGE_B(t + 1, 1);
    SYNC1; MFMA16(4); VMC(8); EBAR;

    // ---- ph3: (t, k1, m0); stage A(t+2, k0) ----
#pragma unroll
    for (int n = 0; n < 4; ++n) bf[n] = RD8(16384 + bBase + n * 1024);
#pragma unroll
    for (int m = 0; m < 4; ++m) af[m] = RD8(16384 + aBase + m * 1024);
    if (more) STAGE_A(t + 2, 0);
    SYNC1; MFMA16(0); EBAR;

    // ---- ph4: (t, k1, m1); stage B(t+2, k0); vmcnt ----
#pragma unroll
    for (int m = 0; m < 4; ++m) af[m] = RD8(16384 + aBase + 4096 + m * 1024);
    if (more) STAGE_B(t + 2, 0);
    SYNC1; MFMA16(4);
    if (more) { VMC(8); } else { VMC(4); }
    EBAR;

    // ---- ph5: (t+1, k0, m0); stage A(t+2, k1) ----
#pragma unroll
    for (int n = 0; n < 4; ++n) bf[n] = RD8(65536 + bBase + n * 1024);
#pragma unroll
    for (int m = 0; m < 4; ++m) af[m] = RD8(65536 + aBase + m * 1024);
    if (more) STAGE_A(t + 2, 1);
    SYNC1; MFMA16(0); EBAR;

    // ---- ph6: (t+1, k0, m1); stage B(t+2, k1); vmcnt ----
#pragma unroll
    for (int m = 0; m < 4; ++m) af[m] = RD8(65536 + aBase + 4096 + m * 1024);
    if (more) STAGE_B(t + 2, 1);
    SYNC1; MFMA16(4);
    if (more) { VMC(8); } else { VMC(0); }
    EBAR;

    // ---- ph7: (t+1, k1, m0); stage A(t+3, k0) ----
#pragma unroll
    for (int n = 0; n < 4; ++n) bf[n] = RD8(65536 + 16384 + bBase + n * 1024);
#pragma unroll
    for (int m = 0; m < 4; ++m) af[m] = RD8(65536 + 16384 + aBase + m * 1024);
    if (more) STAGE_A(t + 3, 0);
    SYNC1; MFMA16(0); EBAR;

    // ---- ph8: (t+1, k1, m1); stage B(t+3, k0); vmcnt(8) ----
#pragma unroll
    for (int m = 0; m < 4; ++m) af[m] = RD8(65536 + 16384 + aBase + 4096 + m * 1024);
    if (more) STAGE_B(t + 3, 0);
    SYNC1; MFMA16(4);
    if (more) { VMC(8); }
    EBAR;
  }

  // epilogue: D layout 16x16x32: col = l15, row-in-16 = lk*4 + r
  // acc[midx][n]: row = row0 + wm*128 + (midx>>2)*64 + (midx&3)*16 + lk*4 + r
#pragma unroll
  for (int midx = 0; midx < 8; ++midx)
#pragma unroll
    for (int n = 0; n < 4; ++n)
#pragma unroll
      for (int r = 0; r < 4; ++r) {
        const long row = row0 + wm * 128 + (midx >> 2) * 64 + (midx & 3) * 16 + lk * 4 + r;
        const long col = col0 + wn * 64 + n * 16 + l15;
        const float v = acc[midx][n][r] + bv[n];
        if (OUT_BF16)
          ((unsigned short*)Cout)[row * ldc + col] = f2bf(v);
        else
          ((float*)Cout)[row * ldc + col] = v;
      }
#undef STAGE_A
#undef STAGE_B
#undef RD8
#undef SBAR
#undef SYNC1
#undef MFMA16
#undef VMC
#undef EBAR
}

__global__ __launch_bounds__(512, 2) void gemm_qkv(const unsigned short* __restrict__ A,
                                                   const unsigned short* __restrict__ Bm,
                                                   const float* __restrict__ bias,
                                                   unsigned short* __restrict__ Cout, int K) {
  gemm256_core<true>(A, Bm, bias, Cout, K, 12, 3072);
}
__global__ __launch_bounds__(512, 2) void gemm_out(const unsigned short* __restrict__ A,
                                                   const unsigned short* __restrict__ Bm,
                                                   const float* __restrict__ bias,
                                                   float* __restrict__ Cout, int K) {
  gemm256_core<false>(A, Bm, bias, Cout, K, 4, 1024);
}

// ---------------- per-token cross-head attention v4: MFMA ----------------
// (unchanged from round 5 -- passed, absmax 0.0039)
__global__ __launch_bounds__(256) void attn_kernel(const unsigned short* __restrict__ qkv,
                                                   unsigned short* __restrict__ out2) {
  __shared__ __align__(16) char lds[4 * 6144];  // 24 KB
  const int tid = threadIdx.x;
  const int wave = tid >> 6;
  const int lane = tid & 63;
  const int token = blockIdx.x * 4 + wave;
  const int l15 = lane & 15;
  const int lk = lane >> 4;
  const int b = token >> 11;
  const int s = token & 2047;

  const char* gbase = (const char*)qkv + (long)token * 6144;
  char* lbase = lds + wave * 6144;
#pragma unroll
  for (int p = 0; p < 6; p++) {
    const int o = p * 1024 + lane * 16;          // linear LDS dest offset
    const int row = o >> 7;                      // 128B row within token
    const int chs = ((o >> 4) & 7) ^ (row & 7);  // pre-swizzled source chunk
    const int src = (o & ~127) | (chs << 4);
    gl2lds16(gbase + src, lbase + o);
  }
  __syncthreads();

  // ---- QK^T (swapped): eT[j][q] = sum_d K[j][d] Q[q][d] ----
  const int sw = l15 & 7;
  const char* qrow = lbase + l15 * 128;
  const char* krow = lbase + 2048 + l15 * 128;
  const short8 kf0 = *(const short8*)(krow + ((lk ^ sw) << 4));
  const short8 kf1 = *(const short8*)(krow + (((lk + 4) ^ sw) << 4));
  const short8 qf0 = *(const short8*)(qrow + ((lk ^ sw) << 4));
  const short8 qf1 = *(const short8*)(qrow + (((lk + 4) ^ sw) << 4));
  floatx4 e = {};
  e = __builtin_amdgcn_mfma_f32_16x16x32_bf16(kf0, qf0, e, 0, 0, 0);
  e = __builtin_amdgcn_mfma_f32_16x16x32_bf16(kf1, qf1, e, 0, 0, 0);

  // ---- softmax over j (4 regs + lanes ^16, ^32); q = l15 stays lane-local ----
  float ev[4];
#pragma unroll
  for (int r = 0; r < 4; ++r) ev[r] = e[r] * 0.03125f;  // / sqrt(1024)
  float mx = fmaxf(fmaxf(ev[0], ev[1]), fmaxf(ev[2], ev[3]));
  mx = fmaxf(mx, __shfl_xor(mx, 16));
  mx = fmaxf(mx, __shfl_xor(mx, 32));
  float sum = 0.f;
#pragma unroll
  for (int r = 0; r < 4; ++r) { ev[r] = __expf(ev[r] - mx); sum += ev[r]; }
  sum += __shfl_xor(sum, 16);
  sum += __shfl_xor(sum, 32);
  const float inv = 1.f / sum;

  // ---- assemble attT B-frag (j-octet lk from lanes (l15,2lk),(l15,2lk+1)) ----
  const uint32_t pa = (uint32_t)f2bf(ev[0] * inv) | ((uint32_t)f2bf(ev[1] * inv) << 16);
  const uint32_t pb = (uint32_t)f2bf(ev[2] * inv) | ((uint32_t)f2bf(ev[3] * inv) << 16);
  const int src0 = (l15 + 32 * lk) & 63;
  uint32_t w0 = __shfl(pa, src0);
  uint32_t w1 = __shfl(pb, src0);
  uint32_t w2 = __shfl(pa, (src0 + 16) & 63);
  uint32_t w3 = __shfl(pb, (src0 + 16) & 63);
  if (lk >= 2) { w0 = 0; w1 = 0; w2 = 0; w3 = 0; }  // zero-pad K 16->32
  union { short8 s8; uint32_t u[4]; } attf;
  attf.u[0] = w0; attf.u[1] = w1; attf.u[2] = w2; attf.u[3] = w3;

  // ---- PV: out^T[d][q] = sum_j V^T[d][j] attT[j][q], 4 d-chunks of 16 ----
  const long orow = (long)b * 2048 + l15 * 128 + (s >> 4);
  unsigned short* op = out2 + orow * 1024 + (long)(s & 15) * 64;
#pragma unroll
  for (int c = 0; c < 4; ++c) {
    union { short8 s8; unsigned short us[8]; } vf;
    if (lk < 2) {
      const int byte_in = (c * 16 + l15) * 2;    // byte within V row (d dim)
#pragma unroll
      for (int i = 0; i < 8; ++i) {
        const int j = lk * 8 + i;
        const int chv = ((byte_in >> 4) ^ (j & 7));  // V rows are token-rows 32+j
        vf.us[i] = *(const unsigned short*)(lbase + 4096 + j * 128 + (chv << 4) +
                                            (byte_in & 15));
      }
    } else {
#pragma unroll
      for (int i = 0; i < 8; ++i) vf.us[i] = 0;    // zero-pad K 16->32
    }
    floatx4 o = {};
    o = __builtin_amdgcn_mfma_f32_16x16x32_bf16(vf.s8, attf.s8, o, 0, 0, 0);
    // lane: out[d = c*16 + lk*4 + r][head q = l15]
    ushort4v r4;
#pragma unroll
    for (int r = 0; r < 4; ++r) r4[r] = f2bf(o[r]);
    *(ushort4v*)(op + c * 16 + lk * 4) = r4;
  }
}

extern "C" void kernel_launch(void* const* d_in, const int* in_sizes, int n_in,
                              void* d_out, int out_size, void* d_ws, size_t ws_size,
                              hipStream_t stream) {
  const float* x    = (const float*)d_in[0];  // [8,2048,1024]
  const float* Wqkv = (const float*)d_in[1];  // [3072,1024]
  const float* bqkv = (const float*)d_in[2];  // [3072]
  const float* Wo   = (const float*)d_in[3];  // [1024,1024]
  const float* bo   = (const float*)d_in[4];  // [1024]
  float* out = (float*)d_out;                 // [8,2048,1024] fp32

  char* ws = (char*)d_ws;
  unsigned short* x_bf    = (unsigned short*)(ws);              // 32 MB
  unsigned short* wqkv_bf = (unsigned short*)(ws + 33554432);   // 6 MB
  unsigned short* wo_bf   = (unsigned short*)(ws + 39845888);   // 2 MB
  unsigned short* qkv_bf  = (unsigned short*)(ws + 41943040);   // 96 MB
  unsigned short* out2_bf = (unsigned short*)(ws + 142606336);  // 32 MB

  cvt_all<<<10240, 256, 0, stream>>>(x, Wqkv, Wo, x_bf, wqkv_bf, wo_bf);

  // qkv = x @ Wqkv^T + bqkv  (M=16384, N=3072, K=1024): 64 x 12 tiles of 256^2
  gemm_qkv<<<64 * 12, 512, 0, stream>>>(x_bf, wqkv_bf, bqkv, qkv_bf, 1024);

  // one wave per token: 16384 tokens / 4 waves per block
  attn_kernel<<<4096, 256, 0, stream>>>(qkv_bf, out2_bf);

  // out = out2 @ Wo^T + bo  (M=16384, N=1024, K=1024): 64 x 4 tiles of 256^2
  gemm_out<<<64 * 4, 512, 0, stream>>>(out2_bf, wo_bf, bo, out, 1024);
}

// Round 10
// 291.011 us; speedup vs baseline: 1.2756x; 1.0239x over previous
//
#include <hip/hip_runtime.h>
#include <hip/hip_bf16.h>
#include <stdint.h>

// B=8, N=2048, E=1024, H=16, D=64 -> M = B*N = 16384.
// qkv row layout per token: [3][H=16][D=64] = 3072 elems (6144 B)

typedef __attribute__((ext_vector_type(8))) short short8;
typedef __attribute__((ext_vector_type(8))) unsigned short ushort8;
typedef __attribute__((ext_vector_type(4))) unsigned short ushort4v;
typedef __attribute__((ext_vector_type(4))) float floatx4;

__device__ __forceinline__ unsigned short f2bf(float f) {
  union { float f; uint32_t u; } x; x.f = f;
  uint32_t u = x.u;
  return (unsigned short)((u + 0x7fffu + ((u >> 16) & 1u)) >> 16);  // RNE
}

// ---------------- fused fp32 -> bf16 cast ----------------
__global__ __launch_bounds__(256) void cvt_all(const float* __restrict__ x,
                                               const float* __restrict__ w1,
                                               const float* __restrict__ w2,
                                               unsigned short* __restrict__ xb,
                                               unsigned short* __restrict__ w1b,
                                               unsigned short* __restrict__ w2b) {
  int i = blockIdx.x * 256 + threadIdx.x;
  const float* src;
  unsigned short* dst;
  if (i < 2097152) {
    src = x; dst = xb;
  } else if (i < 2097152 + 393216) {
    i -= 2097152; src = w1; dst = w1b;
  } else {
    i -= 2490368; src = w2; dst = w2b;
  }
  long base = (long)i * 8;
  const float4* p = (const float4*)(src + base);
  float4 a = p[0], b = p[1];
  ushort8 r;
  r[0] = f2bf(a.x); r[1] = f2bf(a.y); r[2] = f2bf(a.z); r[3] = f2bf(a.w);
  r[4] = f2bf(b.x); r[5] = f2bf(b.y); r[6] = f2bf(b.z); r[7] = f2bf(b.w);
  *(ushort8*)(dst + base) = r;
}

// ---------------- async global->LDS, 16B per lane ----------------
__device__ __forceinline__ void gl2lds16(const void* g, void* l) {
  __builtin_amdgcn_global_load_lds(
      (const uint32_t __attribute__((address_space(1)))*)g,
      (uint32_t __attribute__((address_space(3)))*)(uint32_t)(uintptr_t)l,
      16, 0, 0);
}

// ---------------- bf16 GEMM: C = A*B^T + bias (256x256 tile) ----------------
// GEMM core = round-4/5 measured-good structure (107us qkv / MfmaUtil 41% / 0
// bank conflicts), UNCHANGED sync/schedule. New: template<PERM_A> gather
// staging for gemm_out. attn now writes out2 in TOKEN-NATURAL layout
// [token][q*64+d] (coalesced full-line stores); gemm_out reconstructs the
// scrambled A-row (row=b*2048+q*128+shi, col=slo*64+d) by computing the
// per-lane global source address of each 16B chunk in the natural buffer:
//   token=(b<<11)|(shi<<4)|slo, elem=token*1024+q*64+d; with slo=kt>>1,
//   d0=(kt&1)*32+gch*8; staging row +128 == head q+1 == +64 elems.
// global_load_lds sources are per-lane, so this gather costs the same as the
// old linear-row staging (16B units at ~2KB stride either way).
// Grid: 1D group-of-8-rows so XCD=id%8 pins one A panel per group.
template <bool OUT_BF16, bool PERM_A>
__device__ __forceinline__ void gemm256_core(const unsigned short* __restrict__ A,
                                             const unsigned short* __restrict__ Bm,
                                             const float* __restrict__ bias,
                                             void* __restrict__ Cout,
                                             int K, int ncols, int ldc) {
  __shared__ __align__(16) char lds[131072];
  char* lA = lds;            // 4 bufs x 16KB
  char* lB = lds + 65536;    // 4 bufs x 16KB

  const int id = blockIdx.x;
  const int local = id % (8 * ncols);
  const int brow = (id / (8 * ncols)) * 8 + (local & 7);
  const int bcol = local >> 3;
  const long row0 = (long)brow * 256;
  const long col0 = (long)bcol * 256;

  const int tid = threadIdx.x;
  const int lane = tid & 63;
  const int wave = tid >> 6;
  const int wm = wave >> 2;   // 0..1 (M half)
  const int wn = wave & 3;    // 0..3 (N quarter)
  const int l15 = lane & 15;
  const int lk = lane >> 4;   // k-octet (16B chunk index)

  // Load bias FIRST and drain, so the vmcnt queue holds staging loads only.
  float bv[4];
#pragma unroll
  for (int n = 0; n < 4; ++n) bv[n] = bias[col0 + wn * 64 + n * 16 + l15];
  asm volatile("s_waitcnt vmcnt(0)" ::: "memory");

  // staging: thread t covers LDS row t>>2 (per 128-row round), chunk t&3.
  // global chunk pre-swizzled: gch = (t&3) ^ ((row>>1)&3) = (t&3) ^ ((t>>3)&3)
  const int trow = tid >> 2;
  const int gch = (tid & 3) ^ ((tid >> 3) & 3);
  const unsigned short* gA;
  long rstepA;
  if (PERM_A) {
    // scr-row r = row0+trow: b = brow>>3, q = (brow*2)&15, shi = trow.
    const int b_ = brow >> 3;
    const int q_ = (brow * 2) & 15;
    gA = A + ((long)((b_ << 11) | (trow << 4)) << 10) + q_ * 64 + gch * 8;
    rstepA = 64;                       // row +128 -> head q+1 -> +64 elems
  } else {
    gA = A + (row0 + trow) * (long)K + gch * 8;
    rstepA = (long)128 * K;
  }
  const unsigned short* gB = Bm + (col0 + trow) * (long)K + gch * 8;
  const long rstep = (long)128 * K;
  char* dA = lA + tid * 16;
  char* dB = lB + tid * 16;

  // fragment read offsets (swizzled chunk; (row>>1)&3 == (l15>>1)&3)
  const int ch = ((lk ^ ((l15 >> 1) & 3)) << 4);
  const int aoff = (wm * 128 + l15) * 64 + ch;   // + m*1024 + buf*16384
  const int boff = (wn * 64 + l15) * 64 + ch;    // + n*1024 + buf*16384

  floatx4 acc[8][4] = {};
  const int NT = K >> 5;   // K-tiles of 32

  // prologue: stage tiles 0,1,2 (4 loads each)
#pragma unroll
  for (int t = 0; t < 3; ++t) {
    const long koA = PERM_A ? (long)((t >> 1) * 1024 + (t & 1) * 32) : (long)t * 32;
    const long koB = (long)t * 32;
    gl2lds16(gA + koA, dA + t * 16384);
    gl2lds16(gA + rstepA + koA, dA + t * 16384 + 8192);
    gl2lds16(gB + koB, dB + t * 16384);
    gl2lds16(gB + rstep + koB, dB + t * 16384 + 8192);
  }
  asm volatile("s_waitcnt vmcnt(8)" ::: "memory");  // tile 0 landed
  __builtin_amdgcn_s_barrier();

#pragma unroll 1
  for (int kt = 0; kt < NT; ++kt) {
    const char* bufA = lA + (kt & 3) * 16384;
    const char* bufB = lB + (kt & 3) * 16384;
    const bool stage = (kt + 3 < NT);
    const int ks = kt + 3;
    const long koA = PERM_A ? (long)((ks >> 1) * 1024 + (ks & 1) * 32) : (long)ks * 32;
    const long koB = (long)ks * 32;
    const int sb = (ks & 3) * 16384;

    short8 af[8], bfr[4];
    // cluster-0 deps: bfr0-3 + af0-1 (6 reads, oldest)
#pragma unroll
    for (int n = 0; n < 4; ++n) bfr[n] = *(const short8*)(bufB + boff + n * 1024);
    af[0] = *(const short8*)(bufA + aoff + 0 * 1024);
    af[1] = *(const short8*)(bufA + aoff + 1 * 1024);
    // cluster-1 reads issued ahead
    af[2] = *(const short8*)(bufA + aoff + 2 * 1024);
    af[3] = *(const short8*)(bufA + aoff + 3 * 1024);
    asm volatile("s_waitcnt lgkmcnt(2)" ::: "memory");   // bfr0-3, af0-1 done
    __builtin_amdgcn_sched_barrier(0);
    __builtin_amdgcn_s_setprio(1);
#pragma unroll
    for (int n = 0; n < 4; ++n) {
      acc[0][n] = __builtin_amdgcn_mfma_f32_16x16x32_bf16(af[0], bfr[n], acc[0][n], 0, 0, 0);
      acc[1][n] = __builtin_amdgcn_mfma_f32_16x16x32_bf16(af[1], bfr[n], acc[1][n], 0, 0, 0);
    }
    __builtin_amdgcn_s_setprio(0);
    // cluster-2 reads issued ahead
    af[4] = *(const short8*)(bufA + aoff + 4 * 1024);
    af[5] = *(const short8*)(bufA + aoff + 5 * 1024);
    asm volatile("s_waitcnt lgkmcnt(2)" ::: "memory");   // af2,3 done
    __builtin_amdgcn_sched_barrier(0);
    __builtin_amdgcn_s_setprio(1);
#pragma unroll
    for (int n = 0; n < 4; ++n) {
      acc[2][n] = __builtin_amdgcn_mfma_f32_16x16x32_bf16(af[2], bfr[n], acc[2][n], 0, 0, 0);
      acc[3][n] = __builtin_amdgcn_mfma_f32_16x16x32_bf16(af[3], bfr[n], acc[3][n], 0, 0, 0);
    }
    __builtin_amdgcn_s_setprio(0);
    // cluster-3 reads + next-tile staging issued ahead
    af[6] = *(const short8*)(bufA + aoff + 6 * 1024);
    af[7] = *(const short8*)(bufA + aoff + 7 * 1024);
    if (stage) {
      gl2lds16(gA + koA, dA + sb);
      gl2lds16(gA + rstepA + koA, dA + sb + 8192);
      gl2lds16(gB + koB, dB + sb);
      gl2lds16(gB + rstep + koB, dB + sb + 8192);
    }
    asm volatile("s_waitcnt lgkmcnt(2)" ::: "memory");   // af4,5 done
    __builtin_amdgcn_sched_barrier(0);
    __builtin_amdgcn_s_setprio(1);
#pragma unroll
    for (int n = 0; n < 4; ++n) {
      acc[4][n] = __builtin_amdgcn_mfma_f32_16x16x32_bf16(af[4], bfr[n], acc[4][n], 0, 0, 0);
      acc[5][n] = __builtin_amdgcn_mfma_f32_16x16x32_bf16(af[5], bfr[n], acc[5][n], 0, 0, 0);
    }
    __builtin_amdgcn_s_setprio(0);
    asm volatile("s_waitcnt lgkmcnt(0)" ::: "memory");   // af6,7 done
    __builtin_amdgcn_sched_barrier(0);
    __builtin_amdgcn_s_setprio(1);
#pragma unroll
    for (int n = 0; n < 4; ++n) {
      acc[6][n] = __builtin_amdgcn_mfma_f32_16x16x32_bf16(af[6], bfr[n], acc[6][n], 0, 0, 0);
      acc[7][n] = __builtin_amdgcn_mfma_f32_16x16x32_bf16(af[7], bfr[n], acc[7][n], 0, 0, 0);
    }
    __builtin_amdgcn_s_setprio(0);
    __builtin_amdgcn_sched_barrier(0);
    // window-end counted wait: tile kt+1 must be landed before next window
    if (kt < NT - 3) { asm volatile("s_waitcnt vmcnt(8)" ::: "memory"); }
    else if (kt == NT - 3) { asm volatile("s_waitcnt vmcnt(4)" ::: "memory"); }
    else if (kt == NT - 2) { asm volatile("s_waitcnt vmcnt(0)" ::: "memory"); }
    __builtin_amdgcn_s_barrier();
  }

  // epilogue: C/D layout of 16x16x32: col = lane&15, row = (lane>>4)*4 + reg
  const long crow0 = row0 + wm * 128 + lk * 4;
  const long ccol0 = col0 + wn * 64 + l15;
#pragma unroll
  for (int m = 0; m < 8; ++m)
#pragma unroll
    for (int n = 0; n < 4; ++n)
#pragma unroll
      for (int r = 0; r < 4; ++r) {
        const long row = crow0 + m * 16 + r;
        const long col = ccol0 + n * 16;
        const float v = acc[m][n][r] + bv[n];
        if (OUT_BF16)
          ((unsigned short*)Cout)[row * ldc + col] = f2bf(v);
        else
          ((float*)Cout)[row * ldc + col] = v;
      }
}

__global__ __launch_bounds__(512, 2) void gemm_qkv(const unsigned short* __restrict__ A,
                                                   const unsigned short* __restrict__ Bm,
                                                   const float* __restrict__ bias,
                                                   unsigned short* __restrict__ Cout, int K) {
  gemm256_core<true, false>(A, Bm, bias, Cout, K, 12, 3072);
}
__global__ __launch_bounds__(512, 2) void gemm_out(const unsigned short* __restrict__ A,
                                                   const unsigned short* __restrict__ Bm,
                                                   const float* __restrict__ bias,
                                                   float* __restrict__ Cout, int K) {
  gemm256_core<false, true>(A, Bm, bias, Cout, K, 4, 1024);
}

// ---------------- per-token cross-head attention v5: MFMA + natural store ----
// Same as round-5 v4 (passed, absmax 0.0039) except the output store: out2 is
// now TOKEN-NATURAL [token][q*64+d]. Lane holds out[d=c*16+lk*4+r][q=l15];
// per store c, the wave's 64x8B land inside ONE contiguous 2KB token row
// (16x32B segments, full-line combined across c) instead of 8B granules at
// 256KB stride. gemm_out un-scrambles via gather staging (see above).
__global__ __launch_bounds__(256) void attn_kernel(const unsigned short* __restrict__ qkv,
                                                   unsigned short* __restrict__ out2) {
  __shared__ __align__(16) char lds[4 * 6144];  // 24 KB
  const int tid = threadIdx.x;
  const int wave = tid >> 6;
  const int lane = tid & 63;
  const int token = blockIdx.x * 4 + wave;
  const int l15 = lane & 15;
  const int lk = lane >> 4;

  const char* gbase = (const char*)qkv + (long)token * 6144;
  char* lbase = lds + wave * 6144;
#pragma unroll
  for (int p = 0; p < 6; p++) {
    const int o = p * 1024 + lane * 16;          // linear LDS dest offset
    const int row = o >> 7;                      // 128B row within token
    const int chs = ((o >> 4) & 7) ^ (row & 7);  // pre-swizzled source chunk
    const int src = (o & ~127) | (chs << 4);
    gl2lds16(gbase + src, lbase + o);
  }
  __syncthreads();

  // ---- QK^T (swapped): eT[j][q] = sum_d K[j][d] Q[q][d] ----
  const int sw = l15 & 7;
  const char* qrow = lbase + l15 * 128;
  const char* krow = lbase + 2048 + l15 * 128;
  const short8 kf0 = *(const short8*)(krow + ((lk ^ sw) << 4));
  const short8 kf1 = *(const short8*)(krow + (((lk + 4) ^ sw) << 4));
  const short8 qf0 = *(const short8*)(qrow + ((lk ^ sw) << 4));
  const short8 qf1 = *(const short8*)(qrow + (((lk + 4) ^ sw) << 4));
  floatx4 e = {};
  e = __builtin_amdgcn_mfma_f32_16x16x32_bf16(kf0, qf0, e, 0, 0, 0);
  e = __builtin_amdgcn_mfma_f32_16x16x32_bf16(kf1, qf1, e, 0, 0, 0);

  // ---- softmax over j (4 regs + lanes ^16, ^32); q = l15 stays lane-local ----
  float ev[4];
#pragma unroll
  for (int r = 0; r < 4; ++r) ev[r] = e[r] * 0.03125f;  // / sqrt(1024)
  float mx = fmaxf(fmaxf(ev[0], ev[1]), fmaxf(ev[2], ev[3]));
  mx = fmaxf(mx, __shfl_xor(mx, 16));
  mx = fmaxf(mx, __shfl_xor(mx, 32));
  float sum = 0.f;
#pragma unroll
  for (int r = 0; r < 4; ++r) { ev[r] = __expf(ev[r] - mx); sum += ev[r]; }
  sum += __shfl_xor(sum, 16);
  sum += __shfl_xor(sum, 32);
  const float inv = 1.f / sum;

  // ---- assemble attT B-frag (j-octet lk from lanes (l15,2lk),(l15,2lk+1)) ----
  const uint32_t pa = (uint32_t)f2bf(ev[0] * inv) | ((uint32_t)f2bf(ev[1] * inv) << 16);
  const uint32_t pb = (uint32_t)f2bf(ev[2] * inv) | ((uint32_t)f2bf(ev[3] * inv) << 16);
  const int src0 = (l15 + 32 * lk) & 63;
  uint32_t w0 = __shfl(pa, src0);
  uint32_t w1 = __shfl(pb, src0);
  uint32_t w2 = __shfl(pa, (src0 + 16) & 63);
  uint32_t w3 = __shfl(pb, (src0 + 16) & 63);
  if (lk >= 2) { w0 = 0; w1 = 0; w2 = 0; w3 = 0; }  // zero-pad K 16->32
  union { short8 s8; uint32_t u[4]; } attf;
  attf.u[0] = w0; attf.u[1] = w1; attf.u[2] = w2; attf.u[3] = w3;

  // ---- PV: out^T[d][q] = sum_j V^T[d][j] attT[j][q], 4 d-chunks of 16 ----
  unsigned short* op = out2 + (long)token * 1024 + l15 * 64;  // natural layout
#pragma unroll
  for (int c = 0; c < 4; ++c) {
    union { short8 s8; unsigned short us[8]; } vf;
    if (lk < 2) {
      const int byte_in = (c * 16 + l15) * 2;    // byte within V row (d dim)
#pragma unroll
      for (int i = 0; i < 8; ++i) {
        const int j = lk * 8 + i;
        const int chv = ((byte_in >> 4) ^ (j & 7));  // V rows are token-rows 32+j
        vf.us[i] = *(const unsigned short*)(lbase + 4096 + j * 128 + (chv << 4) +
                                            (byte_in & 15));
      }
    } else {
#pragma unroll
      for (int i = 0; i < 8; ++i) vf.us[i] = 0;    // zero-pad K 16->32
    }
    floatx4 o = {};
    o = __builtin_amdgcn_mfma_f32_16x16x32_bf16(vf.s8, attf.s8, o, 0, 0, 0);
    // lane: out[d = c*16 + lk*4 + r][head q = l15] -> natural [token][q*64+d]
    ushort4v r4;
#pragma unroll
    for (int r = 0; r < 4; ++r) r4[r] = f2bf(o[r]);
    *(ushort4v*)(op + c * 16 + lk * 4) = r4;
  }
}

extern "C" void kernel_launch(void* const* d_in, const int* in_sizes, int n_in,
                              void* d_out, int out_size, void* d_ws, size_t ws_size,
                              hipStream_t stream) {
  const float* x    = (const float*)d_in[0];  // [8,2048,1024]
  const float* Wqkv = (const float*)d_in[1];  // [3072,1024]
  const float* bqkv = (const float*)d_in[2];  // [3072]
  const float* Wo   = (const float*)d_in[3];  // [1024,1024]
  const float* bo   = (const float*)d_in[4];  // [1024]
  float* out = (float*)d_out;                 // [8,2048,1024] fp32

  char* ws = (char*)d_ws;
  unsigned short* x_bf    = (unsigned short*)(ws);              // 32 MB
  unsigned short* wqkv_bf = (unsigned short*)(ws + 33554432);   // 6 MB
  unsigned short* wo_bf   = (unsigned short*)(ws + 39845888);   // 2 MB
  unsigned short* qkv_bf  = (unsigned short*)(ws + 41943040);   // 96 MB
  unsigned short* out2_bf = (unsigned short*)(ws + 142606336);  // 32 MB (natural)

  cvt_all<<<10240, 256, 0, stream>>>(x, Wqkv, Wo, x_bf, wqkv_bf, wo_bf);

  // qkv = x @ Wqkv^T + bqkv  (M=16384, N=3072, K=1024): 64 x 12 tiles of 256^2
  gemm_qkv<<<64 * 12, 512, 0, stream>>>(x_bf, wqkv_bf, bqkv, qkv_bf, 1024);

  // one wave per token: 16384 tokens / 4 waves per block
  attn_kernel<<<4096, 256, 0, stream>>>(qkv_bf, out2_bf);

  // out = out2 @ Wo^T + bo  (M=16384, N=1024, K=1024): 64 x 4 tiles of 256^2
  gemm_out<<<64 * 4, 512, 0, stream>>>(out2_bf, wo_bf, bo, out, 1024);
}